// Round 13
// baseline (349.646 us; speedup 1.0000x reference)
//
#include <hip/hip_runtime.h>
#include <math.h>

// B=2048, C=128, H=4, L=2, P=106, D=32
// 3 launches: PREP, MEGA (1277 blocks x 256 thr: 253 fill-first + 1024 compute
// NB=2; ~25KB LDS -> 6 blocks/CU -> whole grid co-resident), FILL_HEAD (b<24).

#define DEVFN __device__ __forceinline__

typedef float nfloat4 __attribute__((ext_vector_type(4)));

DEVFN void nt_store4(float4* addr, float v){
  nfloat4 val = {v,v,v,v};
  __builtin_nontemporal_store(val, reinterpret_cast<nfloat4*>(addr));
}

DEVFN float wsum(float v){
#pragma unroll
  for (int o=32;o;o>>=1) v += __shfl_xor(v,o);
  return v;
}
DEVFN float wmaxr(float v){
#pragma unroll
  for (int o=32;o;o>>=1) v = fmaxf(v,__shfl_xor(v,o));
  return v;
}
DEVFN float gelu_f(float x){ return 0.5f*x*(1.f+erff(x*0.70710678118654752f)); }
DEVFN float elu_f(float x){ return x>0.f?x:expm1f(x); }
DEVFN float sigm(float x){ return 1.f/(1.f+expf(-x)); }

__global__ __launch_bounds__(256,2) void mega(
  const float* __restrict__ xn_enc_g, const float* __restrict__ Vv_g,
  const float* __restrict__ B1v_g, const float* __restrict__ sb1_g,
  const float* __restrict__ AU, const float* __restrict__ AUT,
  const float* __restrict__ sa1,
  const float* __restrict__ Wcomb, const float* __restrict__ bcomb,
  const float* __restrict__ WvC, const float* __restrict__ bv2,
  const float* __restrict__ Wnv, const float* __restrict__ bnv,
  const float* __restrict__ lin_nw, const float* __restrict__ lin_nb,
  const float* __restrict__ lin_ng, const float* __restrict__ lin_nbeta,
  const float* __restrict__ lin_pg, const float* __restrict__ lin_pbeta,
  const float* __restrict__ ln_pg, const float* __restrict__ ln_pbeta,
  const float* __restrict__ out_nw, const float* __restrict__ out_nb,
  const float* __restrict__ out_pw, const float* __restrict__ out_pb,
  const float* __restrict__ skip_n, const float* __restrict__ skip_p,
  const float* __restrict__ ln_ng, const float* __restrict__ ln_nbeta,
  const float* __restrict__ cls_w, const float* __restrict__ cls_b,
  float* __restrict__ out)
{
  __shared__ __align__(16) float xe[256], x1[256], xA[256], W0s[256], Bv[256], Vvs[256];
  __shared__ __align__(16) float scratch[1024];   // packed-Q / Ys, per-b 512
  __shared__ __align__(16) float ss[1024];        // scores/alpha; head reused as rowd
  __shared__ __align__(16) float rowa[256], rowb[256];
  __shared__ float inv0[256], m1s[256], i1s[256];
  __shared__ __align__(16) float4 PK0[128];       // [w2*64+c] = (Bv2c, ga2c)
  __shared__ __align__(16) float2 PE[128];        // ba+vv
  __shared__ __align__(16) float2 Fa[128];        // omsp*PE + sp0*W0 + vv
  __shared__ __align__(16) float4 G0B0[64];
  __shared__ __align__(16) float x2T[256];        // packed x across 2 b's
  const int tid=threadIdx.x, lane=tid&63, wave=tid>>6, w2=wave>>1, half=wave&1;
  const int bid = blockIdx.x;
  // ---- fill blocks first (bid<253): co-resident store streamers ----
  if (bid < 253){
    float4* att4 = reinterpret_cast<float4*>(out + 4096);
    const long b0 = 24 + (long)bid*8;
#pragma unroll
    for (int r=0;r<8;r++){
      long base=(b0+r)*11449L;
      for (int i=tid;i<11449;i+=256){
        float v=(i>=1&&i<107)?(1.f/217088.f):(1.f/107.f);
        nt_store4(&att4[base+i], v);
      }
    }
    return;
  }
  const int cid = bid - 253;
  const int bbase=cid*2, b=bbase+w2;
  const float sp0=sigm(skip_p[0]), omsp=1.f-sp0, c1=1.f+omsp;
  // stage (256 = 2b x 128)
  xe[tid]=xn_enc_g[(long)bbase*128+tid];
  Bv[tid]=B1v_g[(long)bbase*128+tid];
  Vvs[tid]=Vv_g[(long)bbase*128+tid];
  if (tid<64) G0B0[tid]=make_float4(ln_pg[2*tid],ln_pg[2*tid+1],ln_pbeta[2*tid],ln_pbeta[2*tid+1]);
  __syncthreads();
  // phase1: PK0/PE build + gemv lin_n (4 chains)
  if (tid<128){
    int wp=tid>>6, c=tid&63;
    PK0[tid]=make_float4(Bv[wp*128+2*c],Bv[wp*128+2*c+1],lin_pg[2*c],lin_pg[2*c+1]);
    PE[tid]=make_float2(lin_pbeta[2*c]+Vvs[wp*128+2*c], lin_pbeta[2*c+1]+Vvs[wp*128+2*c+1]);
  }
  {
    const int r=tid>>7, j=tid&127;
    const float4* x4=(const float4*)(xe+r*128);
    float a0=lin_nb[j],a1=0.f,a2=0.f,a3=0.f;
#pragma unroll 4
    for (int i=0;i<32;i++){
      float4 xv=x4[i]; int k=4*i;
      a0+=xv.x*lin_nw[k*128+j]; a1+=xv.y*lin_nw[(k+1)*128+j];
      a2+=xv.z*lin_nw[(k+2)*128+j]; a3+=xv.w*lin_nw[(k+3)*128+j];
    }
    rowa[tid]=(a0+a1)+(a2+a3);
  }
  __syncthreads();
  const float4* AU4=(const float4*)AU;
  const float4* AUT4=(const float4*)AUT;
  const float sb = sb1_g[b];
  const int p = half*64 + lane;
  const bool act = (p<106);
  // phase2: dot sweep (2 chains) + x1 LN + pack
  float iv_reg=0.f;
  if (act){
    float dt0=0.f, dt1=0.f;
#pragma unroll 4
    for (int c=0;c<64;c++){
      float4 au=AUT4[c*128+p];
      float4 pk=PK0[w2*64+c];
      dt0 += au.x*pk.x; dt1 += au.y*pk.y;
    }
    iv_reg = rsqrtf((sa1[p]+2.f*(dt0+dt1)+sb)*(1.f/128.f)+1e-5f);
    inv0[w2*128+p]=iv_reg;
  }
  if (half==0){
    const float* rw=rowa+w2*128;
    float t0=rw[lane], t1=rw[lane+64];
    float m=wsum(t0+t1)*(1.f/128.f);
    float d0=t0-m,d1=t1-m;
    float var=wsum(d0*d0+d1*d1)*(1.f/128.f);
    float inv=rsqrtf(var+1e-5f);
    float v0=d0*inv*lin_ng[lane]   +lin_nbeta[lane]   +xe[w2*128+lane];
    float v1=d1*inv*lin_ng[lane+64]+lin_nbeta[lane+64]+xe[w2*128+lane+64];
    x1[w2*128+lane]=v0; x1[w2*128+lane+64]=v1;
    x2T[lane*2+w2]=v0; x2T[(lane+64)*2+w2]=v1;
  }
  __syncthreads();
  // phase3: dgemv512 L0 -> packed Q (8 chains)
  {
    float b0v=bcomb[tid], b1v=bcomb[256+tid];
    float a00=b0v,a01=b1v,a10=0.f,a11=0.f, c00=0.f,c01=0.f,c10=0.f,c11=0.f;
    const float2* xv2=(const float2*)x2T;
#pragma unroll 4
    for (int k=0;k<128;k+=2){
      float2 xv=xv2[k];  float w0=Wcomb[k*512+tid], w1=Wcomb[k*512+256+tid];
      a00+=xv.x*w0; a01+=xv.x*w1; a10+=xv.y*w0; a11+=xv.y*w1;
      float2 xw=xv2[k+1]; float u0=Wcomb[(k+1)*512+tid], u1=Wcomb[(k+1)*512+256+tid];
      c00+=xw.x*u0; c01+=xw.x*u1; c10+=xw.y*u0; c11+=xw.y*u1;
    }
    // packed layout per b: base = c*8 + (h>>1)*4 + (h&1)*2 + par
    {
      int j=tid, h=j>>7, cc=j&127, c=cc>>1, par=cc&1;
      int base=c*8+(h>>1)*4+(h&1)*2+par;
      scratch[base]=a00+c00; scratch[512+base]=a10+c10;
    }
    {
      int j=tid+256, h=j>>7, cc=j&127, c=cc>>1, par=cc&1;
      int base=c*8+(h>>1)*4+(h&1)*2+par;
      scratch[base]=a01+c01; scratch[512+base]=a11+c11;
    }
  }
  __syncthreads();
  // phase4: L0 score sweep (8 chains via c-parity)
  if (act){
    const float iv=iv_reg;
    const float4* qp=(const float4*)(scratch+w2*512);
    float s0=0,s1=0,s2=0,s3=0, u0=0,u1=0,u2=0,u3=0;
#pragma unroll 2
    for (int c=0;c<64;c+=2){
      {
        float4 au=AUT4[c*128+p];
        float4 pk=PK0[w2*64+c];
        float2 e=PE[w2*64+c];
        float4 Qa=qp[c*2], Qb=qp[c*2+1];
        float rx=(au.x+pk.x)*iv*pk.z + e.x + au.z;
        float ry=(au.y+pk.y)*iv*pk.w + e.y + au.w;
        s0+=rx*Qa.x+ry*Qa.y; s1+=rx*Qa.z+ry*Qa.w;
        s2+=rx*Qb.x+ry*Qb.y; s3+=rx*Qb.z+ry*Qb.w;
      }
      {
        int c2=c+1;
        float4 au=AUT4[c2*128+p];
        float4 pk=PK0[w2*64+c2];
        float2 e=PE[w2*64+c2];
        float4 Qa=qp[c2*2], Qb=qp[c2*2+1];
        float rx=(au.x+pk.x)*iv*pk.z + e.x + au.z;
        float ry=(au.y+pk.y)*iv*pk.w + e.y + au.w;
        u0+=rx*Qa.x+ry*Qa.y; u1+=rx*Qa.z+ry*Qa.w;
        u2+=rx*Qb.x+ry*Qb.y; u3+=rx*Qb.z+ry*Qb.w;
      }
    }
    ss[w2*512+  0+p]=s0+u0; ss[w2*512+128+p]=s1+u1;
    ss[w2*512+256+p]=s2+u2; ss[w2*512+384+p]=s3+u3;
  }
  __syncthreads();
  // phase5: softmax (8 jobs, 2/wave)
#pragma unroll
  for (int k=0;k<2;k++){
    int jj=wave*2+k, jb=jj>>2, jh=jj&3;
    float* row = ss + jb*512 + jh*128;
    float v1=(lane<106)? row[lane] : -1e30f;
    float v2=(lane+64<106)? row[lane+64] : -1e30f;
    float mx=wmaxr(fmaxf(v1,v2));
    float e1=(lane<106)? expf(v1-mx):0.f;
    float e2=(lane+64<106)? expf(v2-mx):0.f;
    float den=wsum(e1+e2);
    float rinv=1.f/den;
    if (lane<106) row[lane]=e1*rinv;
    if (lane+64<106) row[lane+64]=e2*rinv;
  }
  __syncthreads();
  // phase6: L0 pass B (p-range split 53/53 across wave pair)
  float2 yb0,yb1,yb2,yb3;
  {
    float4 pk=PK0[w2*64+lane];
    float2 e=PE[w2*64+lane];
    float2 y0={0,0},y1={0,0},y2={0,0},y3={0,0};
    const float* al = ss + w2*512;
    const float* ivp = inv0 + w2*128;
    const int pst=half*53, pen=pst+53;
    for (int pp=pst; pp<pen; pp++){
      float4 au=AU4[pp*64+lane];
      float ivv=ivp[pp];
      float rx=(au.x+pk.x)*ivv*pk.z+e.x+au.z;
      float ry=(au.y+pk.y)*ivv*pk.w+e.y+au.w;
      float a0=al[pp],a1=al[128+pp],a2=al[256+pp],a3=al[384+pp];
      y0.x+=a0*rx; y0.y+=a0*ry; y1.x+=a1*rx; y1.y+=a1*ry;
      y2.x+=a2*rx; y2.y+=a2*ry; y3.x+=a3*rx; y3.y+=a3*ry;
    }
    yb0=y0; yb1=y1; yb2=y2; yb3=y3;
    if (half==0){
      float2* Yw=(float2*)(scratch+w2*512);
      Yw[lane]=y0; Yw[64+lane]=y1; Yw[128+lane]=y2; Yw[192+lane]=y3;
    }
  }
  __syncthreads();
  if (half==1){
    float2* Yw=(float2*)(scratch+w2*512);
    float2 t;
    t=Yw[lane];     t.x+=yb0.x; t.y+=yb0.y; Yw[lane]=t;
    t=Yw[64+lane];  t.x+=yb1.x; t.y+=yb1.y; Yw[64+lane]=t;
    t=Yw[128+lane]; t.x+=yb2.x; t.y+=yb2.y; Yw[128+lane]=t;
    t=Yw[192+lane]; t.x+=yb3.x; t.y+=yb3.y; Yw[192+lane]=t;
  }
  __syncthreads();
  // phase7: fused agg(WvC)+gemv(Wnv), 2x2 chains, gelu folded
  float* rowd = ss;
  {
    const int r=tid>>7, j=tid&127, h=j>>5, d=j&31;
    const float4* y4=(const float4*)(scratch + r*512 + h*128);
    const float4* x4=(const float4*)(x1 + r*128);
    const float* Wp = WvC + (h*128)*32 + d;
    float a1a=bv2[j], a1b=0.f, a2a=bnv[j], a2b=0.f;
#pragma unroll 2
    for (int i=0;i<32;i+=2){
      float4 yv=y4[i]; float4 xv=x4[i]; int cc=4*i;
      a1a += yv.x*Wp[cc*32]+yv.y*Wp[(cc+1)*32]+yv.z*Wp[(cc+2)*32]+yv.w*Wp[(cc+3)*32];
      a2a += xv.x*Wnv[cc*128+j]+xv.y*Wnv[(cc+1)*128+j]+xv.z*Wnv[(cc+2)*128+j]+xv.w*Wnv[(cc+3)*128+j];
      float4 yv2=y4[i+1]; float4 xv2=x4[i+1]; int c2=4*i+4;
      a1b += yv2.x*Wp[c2*32]+yv2.y*Wp[(c2+1)*32]+yv2.z*Wp[(c2+2)*32]+yv2.w*Wp[(c2+3)*32];
      a2b += xv2.x*Wnv[c2*128+j]+xv2.y*Wnv[(c2+1)*128+j]+xv2.z*Wnv[(c2+2)*128+j]+xv2.w*Wnv[(c2+3)*128+j];
    }
    rowb[tid]=gelu_f(a1a+a1b); rowd[tid]=gelu_f(a2a+a2b);
  }
  __syncthreads();
  // phase8: dual gemv128 (out_nw, out_pw), 2x2 chains
  {
    const int r=tid>>7, j=tid&127;
    const float4* xb=(const float4*)(rowb+r*128);
    const float4* xd=(const float4*)(rowd+r*128);
    float a1a=out_nb[j], a1b=0.f, a2a=out_pb[j], a2b=0.f;
#pragma unroll 2
    for (int i=0;i<32;i+=2){
      float4 bv_=xb[i]; float4 dv=xd[i]; int cc=4*i;
      a1a += bv_.x*out_nw[cc*128+j]+bv_.y*out_nw[(cc+1)*128+j]+bv_.z*out_nw[(cc+2)*128+j]+bv_.w*out_nw[(cc+3)*128+j];
      a2a += dv.x*out_pw[cc*128+j]+dv.y*out_pw[(cc+1)*128+j]+dv.z*out_pw[(cc+2)*128+j]+dv.w*out_pw[(cc+3)*128+j];
      float4 bv2_=xb[i+1]; float4 dv2=xd[i+1]; int c2=4*i+4;
      a1b += bv2_.x*out_nw[c2*128+j]+bv2_.y*out_nw[(c2+1)*128+j]+bv2_.z*out_nw[(c2+2)*128+j]+bv2_.w*out_nw[(c2+3)*128+j];
      a2b += dv2.x*out_pw[c2*128+j]+dv2.y*out_pw[(c2+1)*128+j]+dv2.z*out_pw[(c2+2)*128+j]+dv2.w*out_pw[(c2+3)*128+j];
    }
    rowa[tid]=a1a+a1b; W0s[tid]=a2a+a2b;
  }
  __syncthreads();
  // phase9: xA LN + pack; Fa build
  if (half==0){
    float sn=sigm(skip_n[0]), os=1.f-sn;
    const float* A=rowa+w2*128; const float* Bx=x1+w2*128; const float* R=xe+w2*128;
    float t0=sn*A[lane]+os*Bx[lane]+R[lane];
    float t1=sn*A[lane+64]+os*Bx[lane+64]+R[lane+64];
    float m=wsum(t0+t1)*(1.f/128.f);
    float d0=t0-m,d1=t1-m;
    float var=wsum(d0*d0+d1*d1)*(1.f/128.f);
    float inv=rsqrtf(var+1e-5f);
    float v0=elu_f(d0*inv*ln_ng[lane]+ln_nbeta[lane]);
    float v1=elu_f(d1*inv*ln_ng[lane+64]+ln_nbeta[lane+64]);
    xA[w2*128+lane]=v0; xA[w2*128+lane+64]=v1;
    x2T[lane*2+w2]=v0; x2T[(lane+64)*2+w2]=v1;
  }
  if (tid<128){
    int wp=tid>>6, c=tid&63;
    Fa[tid]=make_float2(omsp*PE[tid].x + sp0*W0s[wp*128+2*c]   + Vvs[wp*128+2*c],
                        omsp*PE[tid].y + sp0*W0s[wp*128+2*c+1] + Vvs[wp*128+2*c+1]);
  }
  __syncthreads();
  // phase10: dgemv512 L1 -> packed Q (8 chains)
  {
    const float* W=Wcomb+65536;
    float b0v=bcomb[512+tid], b1v=bcomb[512+256+tid];
    float a00=b0v,a01=b1v,a10=0.f,a11=0.f, c00=0.f,c01=0.f,c10=0.f,c11=0.f;
    const float2* xv2=(const float2*)x2T;
#pragma unroll 4
    for (int k=0;k<128;k+=2){
      float2 xv=xv2[k];  float w0=W[k*512+tid], w1=W[k*512+256+tid];
      a00+=xv.x*w0; a01+=xv.x*w1; a10+=xv.y*w0; a11+=xv.y*w1;
      float2 xw=xv2[k+1]; float u0=W[(k+1)*512+tid], u1=W[(k+1)*512+256+tid];
      c00+=xw.x*u0; c01+=xw.x*u1; c10+=xw.y*u0; c11+=xw.y*u1;
    }
    {
      int j=tid, h=j>>7, cc=j&127, c=cc>>1, par=cc&1;
      int base=c*8+(h>>1)*4+(h&1)*2+par;
      scratch[base]=a00+c00; scratch[512+base]=a10+c10;
    }
    {
      int j=tid+256, h=j>>7, cc=j&127, c=cc>>1, par=cc&1;
      int base=c*8+(h>>1)*4+(h&1)*2+par;
      scratch[base]=a01+c01; scratch[512+base]=a11+c11;
    }
  }
  __syncthreads();
  // phase11: L1 stats (4 chains) + score sweep (8 chains)
  if (act){
    const float iv=iv_reg;
    float st0=0.f, st1=0.f, sq0=0.f, sq1=0.f;
#pragma unroll 2
    for (int c=0;c<64;c+=2){
      {
        float4 au=AUT4[c*128+p];
        float4 pk=PK0[w2*64+c];
        float2 f=Fa[w2*64+c];
        float t0=omsp*((au.x+pk.x)*iv*pk.z) + f.x + c1*au.z;
        float t1=omsp*((au.y+pk.y)*iv*pk.w) + f.y + c1*au.w;
        st0+=t0+t1; sq0+=t0*t0+t1*t1;
      }
      {
        int c2=c+1;
        float4 au=AUT4[c2*128+p];
        float4 pk=PK0[w2*64+c2];
        float2 f=Fa[w2*64+c2];
        float t0=omsp*((au.x+pk.x)*iv*pk.z) + f.x + c1*au.z;
        float t1=omsp*((au.y+pk.y)*iv*pk.w) + f.y + c1*au.w;
        st1+=t0+t1; sq1+=t0*t0+t1*t1;
      }
    }
    float mA=(st0+st1)*(1.f/128.f);
    float ivA=rsqrtf(fmaxf((sq0+sq1)*(1.f/128.f)-mA*mA,0.f)+1e-5f);
    m1s[w2*128+p]=mA; i1s[w2*128+p]=ivA;
    const float4* qp=(const float4*)(scratch+w2*512);
    float s0=0,s1=0,s2=0,s3=0, u0=0,u1=0,u2=0,u3=0;
#pragma unroll 2
    for (int c=0;c<64;c+=2){
      {
        float4 au=AUT4[c*128+p];
        float4 pk=PK0[w2*64+c];
        float2 f=Fa[w2*64+c];
        float4 gb=G0B0[c];
        float4 Qa=qp[c*2], Qb=qp[c*2+1];
        float t0=omsp*((au.x+pk.x)*iv*pk.z) + f.x + c1*au.z;
        float t1=omsp*((au.y+pk.y)*iv*pk.w) + f.y + c1*au.w;
        float r0=elu_f((t0-mA)*ivA*gb.x+gb.z);
        float r1=elu_f((t1-mA)*ivA*gb.y+gb.w);
        s0+=r0*Qa.x+r1*Qa.y; s1+=r0*Qa.z+r1*Qa.w;
        s2+=r0*Qb.x+r1*Qb.y; s3+=r0*Qb.z+r1*Qb.w;
      }
      {
        int c2=c+1;
        float4 au=AUT4[c2*128+p];
        float4 pk=PK0[w2*64+c2];
        float2 f=Fa[w2*64+c2];
        float4 gb=G0B0[c2];
        float4 Qa=qp[c2*2], Qb=qp[c2*2+1];
        float t0=omsp*((au.x+pk.x)*iv*pk.z) + f.x + c1*au.z;
        float t1=omsp*((au.y+pk.y)*iv*pk.w) + f.y + c1*au.w;
        float r0=elu_f((t0-mA)*ivA*gb.x+gb.z);
        float r1=elu_f((t1-mA)*ivA*gb.y+gb.w);
        u0+=r0*Qa.x+r1*Qa.y; u1+=r0*Qa.z+r1*Qa.w;
        u2+=r0*Qb.x+r1*Qb.y; u3+=r0*Qb.z+r1*Qb.w;
      }
    }
    ss[w2*512+  0+p]=s0+u0; ss[w2*512+128+p]=s1+u1;
    ss[w2*512+256+p]=s2+u2; ss[w2*512+384+p]=s3+u3;
  }
  __syncthreads();
  // phase12: softmax
#pragma unroll
  for (int k=0;k<2;k++){
    int jj=wave*2+k, jb=jj>>2, jh=jj&3;
    float* row = ss + jb*512 + jh*128;
    float v1=(lane<106)? row[lane] : -1e30f;
    float v2=(lane+64<106)? row[lane+64] : -1e30f;
    float mx=wmaxr(fmaxf(v1,v2));
    float e1=(lane<106)? expf(v1-mx):0.f;
    float e2=(lane+64<106)? expf(v2-mx):0.f;
    float den=wsum(e1+e2);
    float rinv=1.f/den;
    if (lane<106) row[lane]=e1*rinv;
    if (lane+64<106) row[lane+64]=e2*rinv;
  }
  __syncthreads();
  // phase13: L1 pass B
  {
    float4 pk=PK0[w2*64+lane];
    float2 f=Fa[w2*64+lane];
    float4 gb=G0B0[lane];
    float2 y0={0,0},y1={0,0},y2={0,0},y3={0,0};
    const float* al = ss + w2*512;
    const float* ivp = inv0 + w2*128;
    const float* mp = m1s + w2*128;
    const float* ip = i1s + w2*128;
    const int pst=half*53, pen=pst+53;
    for (int pp=pst; pp<pen; pp++){
      float4 au=AU4[pp*64+lane];
      float ivv=ivp[pp], m=mp[pp], i2=ip[pp];
      float tx=omsp*((au.x+pk.x)*ivv*pk.z) + f.x + c1*au.z;
      float ty=omsp*((au.y+pk.y)*ivv*pk.w) + f.y + c1*au.w;
      float r0=elu_f((tx-m)*i2*gb.x+gb.z);
      float r1=elu_f((ty-m)*i2*gb.y+gb.w);
      float a0=al[pp],a1=al[128+pp],a2=al[256+pp],a3=al[384+pp];
      y0.x+=a0*r0; y0.y+=a0*r1; y1.x+=a1*r0; y1.y+=a1*r1;
      y2.x+=a2*r0; y2.y+=a2*r1; y3.x+=a3*r0; y3.y+=a3*r1;
    }
    yb0=y0; yb1=y1; yb2=y2; yb3=y3;
    if (half==0){
      float2* Yw=(float2*)(scratch+w2*512);
      Yw[lane]=y0; Yw[64+lane]=y1; Yw[128+lane]=y2; Yw[192+lane]=y3;
    }
  }
  __syncthreads();
  if (half==1){
    float2* Yw=(float2*)(scratch+w2*512);
    float2 t;
    t=Yw[lane];     t.x+=yb0.x; t.y+=yb0.y; Yw[lane]=t;
    t=Yw[64+lane];  t.x+=yb1.x; t.y+=yb1.y; Yw[64+lane]=t;
    t=Yw[128+lane]; t.x+=yb2.x; t.y+=yb2.y; Yw[128+lane]=t;
    t=Yw[192+lane]; t.x+=yb3.x; t.y+=yb3.y; Yw[192+lane]=t;
  }
  __syncthreads();
  // phase14: agg L1 (2 chains, gelu folded)
  {
    const int r=tid>>7, j=tid&127, h=j>>5, d=j&31;
    const float4* y4=(const float4*)(scratch + r*512 + h*128);
    const float* Wp = WvC + 16384 + (h*128)*32 + d;
    float aa=bv2[128+j], ab=0.f;
#pragma unroll 2
    for (int i=0;i<32;i+=2){
      float4 yv=y4[i]; int cc=4*i;
      aa += yv.x*Wp[cc*32]+yv.y*Wp[(cc+1)*32]+yv.z*Wp[(cc+2)*32]+yv.w*Wp[(cc+3)*32];
      float4 yv2=y4[i+1]; int c2=4*i+4;
      ab += yv2.x*Wp[c2*32]+yv2.y*Wp[(c2+1)*32]+yv2.z*Wp[(c2+2)*32]+yv2.w*Wp[(c2+3)*32];
    }
    rowb[tid]=gelu_f(aa+ab);
  }
  __syncthreads();
  // phase15: gemv128 out_nw L1 (2 chains)
  {
    const int r=tid>>7, j=tid&127;
    const float4* xb=(const float4*)(rowb+r*128);
    const float* W=out_nw+16384;
    float aa=out_nb[128+j], ab=0.f;
#pragma unroll 2
    for (int i=0;i<32;i+=2){
      float4 bv_=xb[i]; int cc=4*i;
      aa += bv_.x*W[cc*128+j]+bv_.y*W[(cc+1)*128+j]+bv_.z*W[(cc+2)*128+j]+bv_.w*W[(cc+3)*128+j];
      float4 bv2_=xb[i+1]; int c2=4*i+4;
      ab += bv2_.x*W[c2*128+j]+bv2_.y*W[(c2+1)*128+j]+bv2_.z*W[(c2+2)*128+j]+bv2_.w*W[(c2+3)*128+j];
    }
    rowa[tid]=aa+ab;
  }
  __syncthreads();
  // phase16: final LN + logits
  if (half==0){
    float sn=sigm(skip_n[1]), os=1.f-sn;
    const float* A=rowa+w2*128; const float* Bx=xA+w2*128;
    float t0=sn*A[lane]+os*Bx[lane]+Bx[lane];
    float t1=sn*A[lane+64]+os*Bx[lane+64]+Bx[lane+64];
    float m=wsum(t0+t1)*(1.f/128.f);
    float d0=t0-m,d1=t1-m;
    float var=wsum(d0*d0+d1*d1)*(1.f/128.f);
    float inv=rsqrtf(var+1e-5f);
    float xv0=elu_f(d0*inv*ln_ng[128+lane]+ln_nbeta[128+lane]);
    float xv1=elu_f(d1*inv*ln_ng[128+lane+64]+ln_nbeta[128+lane+64]);
    float a0=xv0*cls_w[lane*2]  +xv1*cls_w[(lane+64)*2];
    float a1=xv0*cls_w[lane*2+1]+xv1*cls_w[(lane+64)*2+1];
    a0=wsum(a0); a1=wsum(a1);
    if (lane==0){ out[b*2]=a0+cls_b[0]; out[b*2+1]=a1+cls_b[1]; }
  }
}

__global__ __launch_bounds__(256) void prep(
  const float* __restrict__ news_emb,
  const float* __restrict__ ctx_w, const float* __restrict__ ctx_b,
  const float* __restrict__ enc_w, const float* __restrict__ enc_b,
  const float* __restrict__ enc_g, const float* __restrict__ enc_beta,
  const float* __restrict__ proj_w, const float* __restrict__ proj_b,
  const float* __restrict__ base_embs,
  const float* __restrict__ fus_w, const float* __restrict__ fus_b,
  const float* __restrict__ lin_pw, const float* __restrict__ lin_pb,
  const float* __restrict__ kqv_nw, const float* __restrict__ kqv_nb,
  const float* __restrict__ kqv_pw, const float* __restrict__ kqv_pb,
  const float* __restrict__ a_rel, const float* __restrict__ m_rel,
  const float* __restrict__ p_rel,
  float* __restrict__ Wcomb, float* __restrict__ bcomb,
  float* __restrict__ WvC, float* __restrict__ bv2,
  float* __restrict__ Wnv, float* __restrict__ bnv,
  float* __restrict__ AU, float* __restrict__ AUT, float* __restrict__ sa1,
  float* __restrict__ xn_enc, float* __restrict__ Vv,
  float* __restrict__ B1v, float* __restrict__ sb1)
{
  __shared__ __align__(16) float pool[6400];
  const int blk=blockIdx.x, tid=threadIdx.x, lane=tid&63, wid=tid>>6;
  if (blk < 135){
    float* sh  = pool;
    float* row1= pool+2048;
    float* row2= pool+2176;
    float* row3= pool+2304;
    float* red = pool+2432;
    if (blk < 16){
      int l=blk>>3, jq=blk&7, h=jq>>1, cc0=(jq&1)*64;
      float* wk = sh;
      float ps = p_rel[(l*2+1)*4+h]*0.17677669529663687f;
      for (int idx=tid; idx<2048; idx+=256){
        int e=idx>>6, cl=idx&63;
        float acc=0.f;
#pragma unroll
        for (int d=0;d<32;d++)
          acc += kqv_pw[(long)l*49152 + (cc0+cl)*384 + h*32 + d]
               * a_rel[((l*2+1)*4+h)*1024 + d*32 + e];
        wk[e*64+cl]=acc*ps;
      }
      __syncthreads();
      for (int idx=tid; idx<8192; idx+=256){
        int c=idx>>6, jl=idx&63;
        float acc=0.f;
#pragma unroll
        for (int e=0;e<32;e++) acc += kqv_nw[(long)l*49152 + c*384 + 128 + h*32 + e]*wk[e*64+jl];
        Wcomb[(long)l*65536 + c*512 + h*128 + cc0 + jl]=acc;
      }
      if (tid<64){
        float acc=0.f;
#pragma unroll
        for (int e=0;e<32;e++) acc += kqv_nb[l*384 + 128 + h*32 + e]*wk[e*64+tid];
        bcomb[l*512 + h*128 + cc0 + tid]=acc;
      }
    } else if (blk < 24){
      int t=blk-16, l=t>>2, h=t&3;
      float* rl = sh;
      for (int i=tid;i<1024;i+=256) rl[i]=m_rel[((l*2+1)*4+h)*1024+i];
      __syncthreads();
      for (int idx=tid; idx<4096; idx+=256){
        int cc=idx>>5, d=idx&31;
        float acc=0.f;
#pragma unroll
        for (int dp=0;dp<32;dp++) acc += kqv_pw[(long)l*49152 + cc*384 + 256 + h*32 + dp]*rl[dp*32+d];
        WvC[l*16384 + (h*128+cc)*32 + d]=acc;
      }
    } else if (blk==24){
      {
        int l=tid>>7, j=tid&127, h=(j>>5)&3, d=j&31;
        float acc=0.f;
#pragma unroll
        for (int dp=0;dp<32;dp++) acc += kqv_pb[l*384+256+h*32+dp]*m_rel[((l*2+1)*4+h)*1024+dp*32+d];
        bv2[l*128+j]=acc;
      }
      if (tid < 128){
        int j=tid, h=j>>5, d=j&31;
        float acc=0.f;
#pragma unroll
        for (int dp=0;dp<32;dp++) acc += kqv_nb[256+h*32+dp]*m_rel[h*1024+dp*32+d];
        bnv[j]=acc;
      }
    } else if (blk < 29){
      int h=blk-25;
      float* rl=sh;
      for (int i=tid;i<1024;i+=256) rl[i]=m_rel[h*1024+i];
      __syncthreads();
      for (int idx=tid; idx<4096; idx+=256){
        int c=idx>>5, d=idx&31;
        float acc=0.f;
#pragma unroll
        for (int dp=0;dp<32;dp++) acc += kqv_nw[c*384+256+h*32+dp]*rl[dp*32+d];
        Wnv[c*128 + h*32 + d]=acc;
      }
    } else {
      int p = blk-29;
      float* xs1=pool;
      int j=tid&127, kg=tid>>7;
      for (int i=tid;i<1024;i+=256) xs1[i]=base_embs[(long)p*1024+i];
      __syncthreads();
      float acc=0.f;
#pragma unroll 4
      for (int k=0;k<512;k++) acc += xs1[kg*512+k]*proj_w[(long)(kg*512+k)*128+j];
      red[tid]=acc; __syncthreads();
      if (tid<128) row1[tid]=red[tid]+red[tid+128]+proj_b[tid];
      __syncthreads();
      acc=0.f;
#pragma unroll 4
      for (int i=0;i<64;i++) acc += row1[kg*64+i]*fus_w[(long)(kg*64+i)*128+j];
      red[tid]=acc; __syncthreads();
      if (tid<128) row2[tid]=red[tid]+red[tid+128]+fus_b[tid];
      __syncthreads();
      acc=0.f;
#pragma unroll 4
      for (int i=0;i<64;i++) acc += row2[kg*64+i]*lin_pw[(long)(kg*64+i)*128+j];
      red[tid]=acc; __syncthreads();
      if (tid<128) row3[tid]=red[tid]+red[tid+128];
      __syncthreads();
      if (wid==0){
        float t0=row3[lane], t1=row3[lane+64];
        float m=wsum(t0+t1)*(1.f/128.f);
        t0-=m; t1-=m;
        float ssq=wsum(t0*t0+t1*t1);
        row3[lane]=t0; row3[lane+64]=t1;
        if (lane==0) sa1[p]=ssq;
      }
      __syncthreads();
      if (tid<64){
        float4 v = make_float4(row3[2*tid],row3[2*tid+1],row2[2*tid],row2[2*tid+1]);
        ((float4*)AU)[p*64+tid]=v;
        ((float4*)AUT)[tid*128+p]=v;
      }
    }
  } else {
    float* xs   = pool;
    float* redL = pool+4096;
    float* rowsC= pool+5120;
    float* Vraw = pool+5632;
    float* bVbL = pool+6144;
    float* bB1L = pool+6272;
    const int r0=(blk-135)*4;
    const int j=tid&127, kg=tid>>7;
    for (int r=0;r<4;r++){
      float4 v=*(const float4*)(news_emb+(long)(r0+r)*1024+tid*4);
      *(float4*)(&xs[r*1024+tid*4])=v;
    }
    {
      float acc=0.f;
#pragma unroll 4
      for (int i=0;i<64;i++) acc += ctx_b[kg*64+i]*fus_w[(128+kg*64+i)*128+j];
      redL[tid]=acc; __syncthreads();
      if (tid<128) bVbL[tid]=redL[tid]+redL[128+tid];
      __syncthreads();
      acc=0.f;
#pragma unroll 4
      for (int i=0;i<64;i++) acc += bVbL[kg*64+i]*lin_pw[(kg*64+i)*128+j];
      redL[tid]=acc; __syncthreads();
      if (tid<128) bB1L[tid]=redL[tid]+redL[128+tid]+lin_pb[tid];
      __syncthreads();
    }
    float ae0=0,ae1=0,ae2=0,ae3=0, ac0=0,ac1=0,ac2=0,ac3=0;
    {
      const float* We=enc_w+(long)(kg*512)*128+j;
      const float* Wc=ctx_w+(long)(kg*512)*128+j;
#pragma unroll 2
      for (int k=0;k<512;k++){
        float we=We[(long)k*128], wc=Wc[(long)k*128];
        float v0=xs[kg*512+k], v1=xs[1024+kg*512+k], v2=xs[2048+kg*512+k], v3=xs[3072+kg*512+k];
        ae0+=v0*we; ae1+=v1*we; ae2+=v2*we; ae3+=v3*we;
        ac0+=v0*wc; ac1+=v1*wc; ac2+=v2*wc; ac3+=v3*wc;
      }
    }
    redL[tid]=ae0; redL[256+tid]=ae1; redL[512+tid]=ae2; redL[768+tid]=ae3;
    __syncthreads();
    {
      float t0=redL[wid*256+lane]+redL[wid*256+128+lane]+enc_b[lane];
      float t1=redL[wid*256+lane+64]+redL[wid*256+128+lane+64]+enc_b[lane+64];
      float m=wsum(t0+t1)*(1.f/128.f);
      float d0=t0-m,d1=t1-m;
      float var=wsum(d0*d0+d1*d1)*(1.f/128.f);
      float inv=rsqrtf(var+1e-5f);
      xn_enc[(long)(r0+wid)*128+lane]   =elu_f(d0*inv*enc_g[lane]   +enc_beta[lane]);
      xn_enc[(long)(r0+wid)*128+lane+64]=elu_f(d1*inv*enc_g[lane+64]+enc_beta[lane+64]);
    }
    __syncthreads();
    redL[tid]=ac0; redL[256+tid]=ac1; redL[512+tid]=ac2; redL[768+tid]=ac3;
    __syncthreads();
    for (int i=tid;i<512;i+=256){
      int r=i>>7,jj=i&127;
      rowsC[r*128+jj]=redL[r*256+jj]+redL[r*256+128+jj];
    }
    __syncthreads();
    {
      const float* Wf=fus_w+(128+kg*64)*128+j;
      float a0=0,a1=0,a2=0,a3=0;
#pragma unroll 4
      for (int i=0;i<64;i++){
        float wv=Wf[i*128];
        a0+=rowsC[kg*64+i]*wv; a1+=rowsC[128+kg*64+i]*wv;
        a2+=rowsC[256+kg*64+i]*wv; a3+=rowsC[384+kg*64+i]*wv;
      }
      redL[tid]=a0; redL[256+tid]=a1; redL[512+tid]=a2; redL[768+tid]=a3;
    }
    __syncthreads();
    for (int i=tid;i<512;i+=256){
      int r=i>>7,jj=i&127;
      float v=redL[r*256+jj]+redL[r*256+128+jj];
      Vraw[r*128+jj]=v;
      Vv[(long)(r0+r)*128+jj]=v+bVbL[jj];
    }
    __syncthreads();
    {
      const float* Wl=lin_pw+(kg*64)*128+j;
      float a0=0,a1=0,a2=0,a3=0;
#pragma unroll 4
      for (int i=0;i<64;i++){
        float wv=Wl[i*128];
        a0+=Vraw[kg*64+i]*wv; a1+=Vraw[128+kg*64+i]*wv;
        a2+=Vraw[256+kg*64+i]*wv; a3+=Vraw[384+kg*64+i]*wv;
      }
      redL[tid]=a0; redL[256+tid]=a1; redL[512+tid]=a2; redL[768+tid]=a3;
    }
    __syncthreads();
    {
      float t0=redL[wid*256+lane]+redL[wid*256+128+lane]+bB1L[lane];
      float t1=redL[wid*256+lane+64]+redL[wid*256+128+lane+64]+bB1L[lane+64];
      float m=wsum(t0+t1)*(1.f/128.f);
      t0-=m; t1-=m;
      float ssq=wsum(t0*t0+t1*t1);
      B1v[(long)(r0+wid)*128+lane]=t0;
      B1v[(long)(r0+wid)*128+lane+64]=t1;
      if (lane==0) sb1[r0+wid]=ssq;
    }
  }
}

__global__ __launch_bounds__(256) void fill_att2(float4* __restrict__ att4){
  const float v1 = 1.f/107.f, v2 = 1.f/217088.f;
  long base = (long)blockIdx.x*11449;
  for (int i=threadIdx.x; i<11449; i+=256){
    float v = (i>=1 && i<107) ? v2 : v1;
    nt_store4(&att4[base+i], v);
  }
}

extern "C" void kernel_launch(void* const* d_in, const int* in_sizes, int n_in,
                              void* d_out, int out_size, void* d_ws, size_t ws_size,
                              hipStream_t stream) {
  const float* news_emb = (const float*)d_in[0];
  const float* base_embs= (const float*)d_in[1];
  const float* ctx_w  = (const float*)d_in[2];
  const float* ctx_b  = (const float*)d_in[3];
  const float* proj_w = (const float*)d_in[4];
  const float* proj_b = (const float*)d_in[5];
  const float* fus_w  = (const float*)d_in[6];
  const float* fus_b  = (const float*)d_in[7];
  const float* enc_w  = (const float*)d_in[8];
  const float* enc_b  = (const float*)d_in[9];
  const float* enc_g  = (const float*)d_in[10];
  const float* enc_beta=(const float*)d_in[11];
  const float* lin_nw = (const float*)d_in[12];
  const float* lin_nb = (const float*)d_in[13];
  const float* lin_ng = (const float*)d_in[14];
  const float* lin_nbeta=(const float*)d_in[15];
  const float* kqv_nw = (const float*)d_in[16];
  const float* kqv_nb = (const float*)d_in[17];
  const float* out_nw = (const float*)d_in[18];
  const float* out_nb = (const float*)d_in[19];
  const float* skip_n = (const float*)d_in[20];
  const float* ln_ng  = (const float*)d_in[21];
  const float* ln_nbeta=(const float*)d_in[22];
  const float* lin_pw = (const float*)d_in[23];
  const float* lin_pb = (const float*)d_in[24];
  const float* lin_pg = (const float*)d_in[25];
  const float* lin_pbeta=(const float*)d_in[26];
  const float* kqv_pw = (const float*)d_in[27];
  const float* kqv_pb = (const float*)d_in[28];
  const float* out_pw = (const float*)d_in[29];
  const float* out_pb = (const float*)d_in[30];
  const float* skip_p = (const float*)d_in[31];
  const float* ln_pg  = (const float*)d_in[32];
  const float* ln_pbeta=(const float*)d_in[33];
  const float* a_rel  = (const float*)d_in[34];
  const float* m_rel  = (const float*)d_in[35];
  const float* p_rel  = (const float*)d_in[36];
  const float* cls_w  = (const float*)d_in[37];
  const float* cls_b  = (const float*)d_in[38];
  (void)in_sizes; (void)n_in; (void)out_size; (void)d_ws; (void)ws_size;

  float* out = (float*)d_out;
  float* S = out + 4096;            // scratch inside b<24 att zone; head-filled last
  float* xn_enc = S + 0;
  float* Vv     = S + 262144;
  float* B1v    = S + 524288;
  float* sb1    = S + 786432;
  float* sa1    = S + 788480;
  float* AU     = S + 788608;
  float* AUT    = S + 815744;
  float* WvC    = S + 848512;
  float* bv2    = S + 881280;
  float* Wnv    = S + 881536;
  float* bnv    = S + 897920;
  float* Wcomb  = S + 898048;
  float* bcomb  = S + 1029120;

  dim3 blk(256);
  prep<<<647,blk,0,stream>>>(news_emb,ctx_w,ctx_b,enc_w,enc_b,enc_g,enc_beta,
      proj_w,proj_b,base_embs,fus_w,fus_b,lin_pw,lin_pb,
      kqv_nw,kqv_nb,kqv_pw,kqv_pb,a_rel,m_rel,p_rel,
      Wcomb,bcomb,WvC,bv2,Wnv,bnv,AU,AUT,sa1,xn_enc,Vv,B1v,sb1);
  mega<<<1277,blk,0,stream>>>(xn_enc,Vv,B1v,sb1,AU,AUT,sa1,Wcomb,bcomb,WvC,bv2,Wnv,bnv,
      lin_nw,lin_nb,lin_ng,lin_nbeta,lin_pg,lin_pbeta,ln_pg,ln_pbeta,
      out_nw,out_nb,out_pw,out_pb,skip_n,skip_p,ln_ng,ln_nbeta,cls_w,cls_b,out);
  fill_att2<<<24,blk,0,stream>>>(reinterpret_cast<float4*>(S));
}

// Round 14
// 297.078 us; speedup vs baseline: 1.1770x; 1.1770x over previous
//
#include <hip/hip_runtime.h>
#include <math.h>

// B=2048, C=128, H=4, L=2, P=106, D=32
// 3 launches: PREP, MEGA (512 blocks x 512 thr, NB=4; att fill as per-block
// epilogue after compute), FILL_HEAD (b<24).

#define DEVFN __device__ __forceinline__

typedef float nfloat4 __attribute__((ext_vector_type(4)));

DEVFN void nt_store4(float4* addr, float v){
  nfloat4 val = {v,v,v,v};
  __builtin_nontemporal_store(val, reinterpret_cast<nfloat4*>(addr));
}

DEVFN float wsum(float v){
#pragma unroll
  for (int o=32;o;o>>=1) v += __shfl_xor(v,o);
  return v;
}
DEVFN float wmaxr(float v){
#pragma unroll
  for (int o=32;o;o>>=1) v = fmaxf(v,__shfl_xor(v,o));
  return v;
}
DEVFN float gelu_f(float x){ return 0.5f*x*(1.f+erff(x*0.70710678118654752f)); }
DEVFN float elu_f(float x){ return x>0.f?x:expm1f(x); }
DEVFN float sigm(float x){ return 1.f/(1.f+expf(-x)); }

__global__ __launch_bounds__(512,2) void mega(
  const float* __restrict__ xn_enc_g, const float* __restrict__ Vv_g,
  const float* __restrict__ B1v_g, const float* __restrict__ sb1_g,
  const float* __restrict__ AU, const float* __restrict__ AUT,
  const float* __restrict__ sa1,
  const float* __restrict__ Wcomb, const float* __restrict__ bcomb,
  const float* __restrict__ WvC, const float* __restrict__ bv2,
  const float* __restrict__ Wnv, const float* __restrict__ bnv,
  const float* __restrict__ lin_nw, const float* __restrict__ lin_nb,
  const float* __restrict__ lin_ng, const float* __restrict__ lin_nbeta,
  const float* __restrict__ lin_pg, const float* __restrict__ lin_pbeta,
  const float* __restrict__ ln_pg, const float* __restrict__ ln_pbeta,
  const float* __restrict__ out_nw, const float* __restrict__ out_nb,
  const float* __restrict__ out_pw, const float* __restrict__ out_pb,
  const float* __restrict__ skip_n, const float* __restrict__ skip_p,
  const float* __restrict__ ln_ng, const float* __restrict__ ln_nbeta,
  const float* __restrict__ cls_w, const float* __restrict__ cls_b,
  float* __restrict__ out)
{
  __shared__ __align__(16) float xe[512], x1[512], xA[512], W0s[512], Bv[512], Vvs[512];
  __shared__ __align__(16) float scratch[2048];
  __shared__ __align__(16) float ss[2048];
  __shared__ __align__(16) float rowa[512], rowb[512];
  __shared__ float inv0[512], m1s[512], i1s[512];
  __shared__ __align__(16) float4 PK0[256];
  __shared__ __align__(16) float2 PE[256];
  __shared__ __align__(16) float2 Fa[256];
  __shared__ __align__(16) float4 G0B0[64];
  __shared__ __align__(16) float x4T[512];
  const int tid=threadIdx.x, lane=tid&63, wave=tid>>6, w2=wave>>1, half=wave&1;
  const int cid = blockIdx.x;
  const int bbase=cid*4, b=bbase+w2;
  const float sp0=sigm(skip_p[0]), omsp=1.f-sp0, c1=1.f+omsp;
  // stage
  xe[tid]=xn_enc_g[(long)bbase*128+tid];
  Bv[tid]=B1v_g[(long)bbase*128+tid];
  Vvs[tid]=Vv_g[(long)bbase*128+tid];
  if (tid<64) G0B0[tid]=make_float4(ln_pg[2*tid],ln_pg[2*tid+1],ln_pbeta[2*tid],ln_pbeta[2*tid+1]);
  __syncthreads();
  // phase1: build PK0/PE + gemv (lin_n), 4-acc
  if (tid<256){
    int wp=tid>>6, c=tid&63;
    float bx=Bv[wp*128+2*c], by=Bv[wp*128+2*c+1];
    PK0[tid]=make_float4(bx,by,lin_pg[2*c],lin_pg[2*c+1]);
    PE[tid]=make_float2(lin_pbeta[2*c]+Vvs[wp*128+2*c], lin_pbeta[2*c+1]+Vvs[wp*128+2*c+1]);
  }
  {
    const int r=tid>>7, j=tid&127;
    const float4* x4=(const float4*)(xe+r*128);
    float a0=lin_nb[j],a1=0.f,a2=0.f,a3=0.f;
#pragma unroll 4
    for (int i=0;i<32;i++){
      float4 xv=x4[i]; int k=4*i;
      a0+=xv.x*lin_nw[k*128+j]; a1+=xv.y*lin_nw[(k+1)*128+j];
      a2+=xv.z*lin_nw[(k+2)*128+j]; a3+=xv.w*lin_nw[(k+3)*128+j];
    }
    rowa[tid]=(a0+a1)+(a2+a3);
  }
  __syncthreads();
  const float4* AU4=(const float4*)AU;
  const float4* AUT4=(const float4*)AUT;
  const float sb = sb1_g[b];
  const int p = half*64 + lane;
  const bool act = (p<106);
  // phase2: dot sweep (2 chains) + x1 LN
  float iv_reg=0.f;
  if (act){
    float dt0=0.f, dt1=0.f;
#pragma unroll 4
    for (int c=0;c<64;c++){
      float4 au=AUT4[c*128+p];
      float4 pk=PK0[w2*64+c];
      dt0 += au.x*pk.x; dt1 += au.y*pk.y;
    }
    iv_reg = rsqrtf((sa1[p]+2.f*(dt0+dt1)+sb)*(1.f/128.f)+1e-5f);
    inv0[w2*128+p]=iv_reg;
  }
  if (half==0){
    const float* rw=rowa+w2*128;
    float t0=rw[lane], t1=rw[lane+64];
    float m=wsum(t0+t1)*(1.f/128.f);
    float d0=t0-m,d1=t1-m;
    float var=wsum(d0*d0+d1*d1)*(1.f/128.f);
    float inv=rsqrtf(var+1e-5f);
    float v0=d0*inv*lin_ng[lane]   +lin_nbeta[lane]   +xe[w2*128+lane];
    float v1=d1*inv*lin_ng[lane+64]+lin_nbeta[lane+64]+xe[w2*128+lane+64];
    x1[w2*128+lane]=v0; x1[w2*128+lane+64]=v1;
    x4T[lane*4+w2]=v0; x4T[(lane+64)*4+w2]=v1;
  }
  __syncthreads();
  // phase3: dgemv512 L0 -> packed Q (8 chains)
  {
    float bval=bcomb[tid];
    float p0=bval,p1=bval,p2=bval,p3=bval, q0=0.f,q1=0.f,q2=0.f,q3=0.f;
    const float4* xv4=(const float4*)x4T;
#pragma unroll 4
    for (int k=0;k<128;k+=2){
      float4 xv=xv4[k];  float w=Wcomb[k*512+tid];
      p0+=xv.x*w; p1+=xv.y*w; p2+=xv.z*w; p3+=xv.w*w;
      float4 xv2=xv4[k+1]; float w2=Wcomb[(k+1)*512+tid];
      q0+=xv2.x*w2; q1+=xv2.y*w2; q2+=xv2.z*w2; q3+=xv2.w*w2;
    }
    int h=tid>>7, cc=tid&127, c=cc>>1, par=cc&1;
    int base = c*8 + (h>>1)*4 + (h&1)*2 + par;
    scratch[base]=p0+q0; scratch[512+base]=p1+q1; scratch[1024+base]=p2+q2; scratch[1536+base]=p3+q3;
  }
  __syncthreads();
  // phase4: L0 score sweep (8 chains via c-parity)
  if (act){
    const float iv=iv_reg;
    const float4* qp=(const float4*)(scratch+w2*512);
    float s0=0,s1=0,s2=0,s3=0, u0=0,u1=0,u2=0,u3=0;
#pragma unroll 2
    for (int c=0;c<64;c+=2){
      {
        float4 au=AUT4[c*128+p];
        float4 pk=PK0[w2*64+c];
        float2 e=PE[w2*64+c];
        float4 Qa=qp[c*2], Qb=qp[c*2+1];
        float rx=(au.x+pk.x)*iv*pk.z + e.x + au.z;
        float ry=(au.y+pk.y)*iv*pk.w + e.y + au.w;
        s0+=rx*Qa.x+ry*Qa.y; s1+=rx*Qa.z+ry*Qa.w;
        s2+=rx*Qb.x+ry*Qb.y; s3+=rx*Qb.z+ry*Qb.w;
      }
      {
        int c2=c+1;
        float4 au=AUT4[c2*128+p];
        float4 pk=PK0[w2*64+c2];
        float2 e=PE[w2*64+c2];
        float4 Qa=qp[c2*2], Qb=qp[c2*2+1];
        float rx=(au.x+pk.x)*iv*pk.z + e.x + au.z;
        float ry=(au.y+pk.y)*iv*pk.w + e.y + au.w;
        u0+=rx*Qa.x+ry*Qa.y; u1+=rx*Qa.z+ry*Qa.w;
        u2+=rx*Qb.x+ry*Qb.y; u3+=rx*Qb.z+ry*Qb.w;
      }
    }
    ss[w2*512+  0+p]=s0+u0; ss[w2*512+128+p]=s1+u1;
    ss[w2*512+256+p]=s2+u2; ss[w2*512+384+p]=s3+u3;
  }
  __syncthreads();
  // phase5: softmax (16 jobs, 2/wave)
#pragma unroll
  for (int k=0;k<2;k++){
    int jj=wave*2+k, jb=jj>>2, jh=jj&3;
    float* row = ss + jb*512 + jh*128;
    float v1=(lane<106)? row[lane] : -1e30f;
    float v2=(lane+64<106)? row[lane+64] : -1e30f;
    float mx=wmaxr(fmaxf(v1,v2));
    float e1=(lane<106)? expf(v1-mx):0.f;
    float e2=(lane+64<106)? expf(v2-mx):0.f;
    float den=wsum(e1+e2);
    float rinv=1.f/den;
    if (lane<106) row[lane]=e1*rinv;
    if (lane+64<106) row[lane+64]=e2*rinv;
  }
  __syncthreads();
  // phase6: L0 pass B
  float2 yb0,yb1,yb2,yb3;
  {
    float4 pk=PK0[w2*64+lane];
    float2 e=PE[w2*64+lane];
    float2 y0={0,0},y1={0,0},y2={0,0},y3={0,0};
    const float* al = ss + w2*512;
    const float* ivp = inv0 + w2*128;
    const int pst=half*53, pen=pst+53;
    for (int pp=pst; pp<pen; pp++){
      float4 au=AU4[pp*64+lane];
      float ivv=ivp[pp];
      float rx=(au.x+pk.x)*ivv*pk.z+e.x+au.z;
      float ry=(au.y+pk.y)*ivv*pk.w+e.y+au.w;
      float a0=al[pp],a1=al[128+pp],a2=al[256+pp],a3=al[384+pp];
      y0.x+=a0*rx; y0.y+=a0*ry; y1.x+=a1*rx; y1.y+=a1*ry;
      y2.x+=a2*rx; y2.y+=a2*ry; y3.x+=a3*rx; y3.y+=a3*ry;
    }
    yb0=y0; yb1=y1; yb2=y2; yb3=y3;
    if (half==0){
      float2* Yw=(float2*)(scratch+w2*512);
      Yw[lane]=y0; Yw[64+lane]=y1; Yw[128+lane]=y2; Yw[192+lane]=y3;
    }
  }
  __syncthreads();
  if (half==1){
    float2* Yw=(float2*)(scratch+w2*512);
    float2 t;
    t=Yw[lane];     t.x+=yb0.x; t.y+=yb0.y; Yw[lane]=t;
    t=Yw[64+lane];  t.x+=yb1.x; t.y+=yb1.y; Yw[64+lane]=t;
    t=Yw[128+lane]; t.x+=yb2.x; t.y+=yb2.y; Yw[128+lane]=t;
    t=Yw[192+lane]; t.x+=yb3.x; t.y+=yb3.y; Yw[192+lane]=t;
  }
  __syncthreads();
  // phase7: fused agg(WvC)+gemv(Wnv), 2x2 chains, gelu folded
  float* rowd = ss + 512;
  {
    const int r=tid>>7, j=tid&127, h=j>>5, d=j&31;
    const float4* y4=(const float4*)(scratch + r*512 + h*128);
    const float4* x4=(const float4*)(x1 + r*128);
    const float* Wp = WvC + (h*128)*32 + d;
    float a1a=bv2[j], a1b=0.f, a2a=bnv[j], a2b=0.f;
#pragma unroll 2
    for (int i=0;i<32;i+=2){
      float4 yv=y4[i]; float4 xv=x4[i]; int cc=4*i;
      a1a += yv.x*Wp[cc*32]+yv.y*Wp[(cc+1)*32]+yv.z*Wp[(cc+2)*32]+yv.w*Wp[(cc+3)*32];
      a2a += xv.x*Wnv[cc*128+j]+xv.y*Wnv[(cc+1)*128+j]+xv.z*Wnv[(cc+2)*128+j]+xv.w*Wnv[(cc+3)*128+j];
      float4 yv2=y4[i+1]; float4 xv2=x4[i+1]; int c2=4*i+4;
      a1b += yv2.x*Wp[c2*32]+yv2.y*Wp[(c2+1)*32]+yv2.z*Wp[(c2+2)*32]+yv2.w*Wp[(c2+3)*32];
      a2b += xv2.x*Wnv[c2*128+j]+xv2.y*Wnv[(c2+1)*128+j]+xv2.z*Wnv[(c2+2)*128+j]+xv2.w*Wnv[(c2+3)*128+j];
    }
    rowb[tid]=gelu_f(a1a+a1b); rowd[tid]=gelu_f(a2a+a2b);
  }
  __syncthreads();
  // phase8: dual gemv128 (out_nw, out_pw), 2x2 chains
  {
    const int r=tid>>7, j=tid&127;
    const float4* xb=(const float4*)(rowb+r*128);
    const float4* xd=(const float4*)(rowd+r*128);
    float a1a=out_nb[j], a1b=0.f, a2a=out_pb[j], a2b=0.f;
#pragma unroll 2
    for (int i=0;i<32;i+=2){
      float4 bv_=xb[i]; float4 dv=xd[i]; int cc=4*i;
      a1a += bv_.x*out_nw[cc*128+j]+bv_.y*out_nw[(cc+1)*128+j]+bv_.z*out_nw[(cc+2)*128+j]+bv_.w*out_nw[(cc+3)*128+j];
      a2a += dv.x*out_pw[cc*128+j]+dv.y*out_pw[(cc+1)*128+j]+dv.z*out_pw[(cc+2)*128+j]+dv.w*out_pw[(cc+3)*128+j];
      float4 bv2_=xb[i+1]; float4 dv2=xd[i+1]; int c2=4*i+4;
      a1b += bv2_.x*out_nw[c2*128+j]+bv2_.y*out_nw[(c2+1)*128+j]+bv2_.z*out_nw[(c2+2)*128+j]+bv2_.w*out_nw[(c2+3)*128+j];
      a2b += dv2.x*out_pw[c2*128+j]+dv2.y*out_pw[(c2+1)*128+j]+dv2.z*out_pw[(c2+2)*128+j]+dv2.w*out_pw[(c2+3)*128+j];
    }
    rowa[tid]=a1a+a1b; W0s[tid]=a2a+a2b;
  }
  __syncthreads();
  // phase9: xA LN + pack; Fa build
  if (half==0){
    float sn=sigm(skip_n[0]), os=1.f-sn;
    const float* A=rowa+w2*128; const float* Bx=x1+w2*128; const float* R=xe+w2*128;
    float t0=sn*A[lane]+os*Bx[lane]+R[lane];
    float t1=sn*A[lane+64]+os*Bx[lane+64]+R[lane+64];
    float m=wsum(t0+t1)*(1.f/128.f);
    float d0=t0-m,d1=t1-m;
    float var=wsum(d0*d0+d1*d1)*(1.f/128.f);
    float inv=rsqrtf(var+1e-5f);
    float v0=elu_f(d0*inv*ln_ng[lane]+ln_nbeta[lane]);
    float v1=elu_f(d1*inv*ln_ng[lane+64]+ln_nbeta[lane+64]);
    xA[w2*128+lane]=v0; xA[w2*128+lane+64]=v1;
    x4T[lane*4+w2]=v0; x4T[(lane+64)*4+w2]=v1;
  }
  if (tid<256){
    int wp=tid>>6, c=tid&63;
    Fa[tid]=make_float2(omsp*PE[tid].x + sp0*W0s[wp*128+2*c]   + Vvs[wp*128+2*c],
                        omsp*PE[tid].y + sp0*W0s[wp*128+2*c+1] + Vvs[wp*128+2*c+1]);
  }
  __syncthreads();
  // phase10: dgemv512 L1 -> packed Q (8 chains)
  {
    float bval=bcomb[512+tid];
    float p0=bval,p1=bval,p2=bval,p3=bval, q0=0.f,q1=0.f,q2=0.f,q3=0.f;
    const float4* xv4=(const float4*)x4T;
    const float* W=Wcomb+65536;
#pragma unroll 4
    for (int k=0;k<128;k+=2){
      float4 xv=xv4[k];  float w=W[k*512+tid];
      p0+=xv.x*w; p1+=xv.y*w; p2+=xv.z*w; p3+=xv.w*w;
      float4 xv2=xv4[k+1]; float w2=W[(k+1)*512+tid];
      q0+=xv2.x*w2; q1+=xv2.y*w2; q2+=xv2.z*w2; q3+=xv2.w*w2;
    }
    int h=tid>>7, cc=tid&127, c=cc>>1, par=cc&1;
    int base = c*8 + (h>>1)*4 + (h&1)*2 + par;
    scratch[base]=p0+q0; scratch[512+base]=p1+q1; scratch[1024+base]=p2+q2; scratch[1536+base]=p3+q3;
  }
  __syncthreads();
  // phase11: L1 stats (4 chains) + score sweep (8 chains)
  if (act){
    const float iv=iv_reg;
    float st0=0.f, st1=0.f, sq0=0.f, sq1=0.f;
#pragma unroll 2
    for (int c=0;c<64;c+=2){
      {
        float4 au=AUT4[c*128+p];
        float4 pk=PK0[w2*64+c];
        float2 f=Fa[w2*64+c];
        float t0=omsp*((au.x+pk.x)*iv*pk.z) + f.x + c1*au.z;
        float t1=omsp*((au.y+pk.y)*iv*pk.w) + f.y + c1*au.w;
        st0+=t0+t1; sq0+=t0*t0+t1*t1;
      }
      {
        int c2=c+1;
        float4 au=AUT4[c2*128+p];
        float4 pk=PK0[w2*64+c2];
        float2 f=Fa[w2*64+c2];
        float t0=omsp*((au.x+pk.x)*iv*pk.z) + f.x + c1*au.z;
        float t1=omsp*((au.y+pk.y)*iv*pk.w) + f.y + c1*au.w;
        st1+=t0+t1; sq1+=t0*t0+t1*t1;
      }
    }
    float mA=(st0+st1)*(1.f/128.f);
    float ivA=rsqrtf(fmaxf((sq0+sq1)*(1.f/128.f)-mA*mA,0.f)+1e-5f);
    m1s[w2*128+p]=mA; i1s[w2*128+p]=ivA;
    const float4* qp=(const float4*)(scratch+w2*512);
    float s0=0,s1=0,s2=0,s3=0, u0=0,u1=0,u2=0,u3=0;
#pragma unroll 2
    for (int c=0;c<64;c+=2){
      {
        float4 au=AUT4[c*128+p];
        float4 pk=PK0[w2*64+c];
        float2 f=Fa[w2*64+c];
        float4 gb=G0B0[c];
        float4 Qa=qp[c*2], Qb=qp[c*2+1];
        float t0=omsp*((au.x+pk.x)*iv*pk.z) + f.x + c1*au.z;
        float t1=omsp*((au.y+pk.y)*iv*pk.w) + f.y + c1*au.w;
        float r0=elu_f((t0-mA)*ivA*gb.x+gb.z);
        float r1=elu_f((t1-mA)*ivA*gb.y+gb.w);
        s0+=r0*Qa.x+r1*Qa.y; s1+=r0*Qa.z+r1*Qa.w;
        s2+=r0*Qb.x+r1*Qb.y; s3+=r0*Qb.z+r1*Qb.w;
      }
      {
        int c2=c+1;
        float4 au=AUT4[c2*128+p];
        float4 pk=PK0[w2*64+c2];
        float2 f=Fa[w2*64+c2];
        float4 gb=G0B0[c2];
        float4 Qa=qp[c2*2], Qb=qp[c2*2+1];
        float t0=omsp*((au.x+pk.x)*iv*pk.z) + f.x + c1*au.z;
        float t1=omsp*((au.y+pk.y)*iv*pk.w) + f.y + c1*au.w;
        float r0=elu_f((t0-mA)*ivA*gb.x+gb.z);
        float r1=elu_f((t1-mA)*ivA*gb.y+gb.w);
        u0+=r0*Qa.x+r1*Qa.y; u1+=r0*Qa.z+r1*Qa.w;
        u2+=r0*Qb.x+r1*Qb.y; u3+=r0*Qb.z+r1*Qb.w;
      }
    }
    ss[w2*512+  0+p]=s0+u0; ss[w2*512+128+p]=s1+u1;
    ss[w2*512+256+p]=s2+u2; ss[w2*512+384+p]=s3+u3;
  }
  __syncthreads();
  // phase12: softmax
#pragma unroll
  for (int k=0;k<2;k++){
    int jj=wave*2+k, jb=jj>>2, jh=jj&3;
    float* row = ss + jb*512 + jh*128;
    float v1=(lane<106)? row[lane] : -1e30f;
    float v2=(lane+64<106)? row[lane+64] : -1e30f;
    float mx=wmaxr(fmaxf(v1,v2));
    float e1=(lane<106)? expf(v1-mx):0.f;
    float e2=(lane+64<106)? expf(v2-mx):0.f;
    float den=wsum(e1+e2);
    float rinv=1.f/den;
    if (lane<106) row[lane]=e1*rinv;
    if (lane+64<106) row[lane+64]=e2*rinv;
  }
  __syncthreads();
  // phase13: L1 pass B
  {
    float4 pk=PK0[w2*64+lane];
    float2 f=Fa[w2*64+lane];
    float4 gb=G0B0[lane];
    float2 y0={0,0},y1={0,0},y2={0,0},y3={0,0};
    const float* al = ss + w2*512;
    const float* ivp = inv0 + w2*128;
    const float* mp = m1s + w2*128;
    const float* ip = i1s + w2*128;
    const int pst=half*53, pen=pst+53;
    for (int pp=pst; pp<pen; pp++){
      float4 au=AU4[pp*64+lane];
      float ivv=ivp[pp], m=mp[pp], i2=ip[pp];
      float tx=omsp*((au.x+pk.x)*ivv*pk.z) + f.x + c1*au.z;
      float ty=omsp*((au.y+pk.y)*ivv*pk.w) + f.y + c1*au.w;
      float r0=elu_f((tx-m)*i2*gb.x+gb.z);
      float r1=elu_f((ty-m)*i2*gb.y+gb.w);
      float a0=al[pp],a1=al[128+pp],a2=al[256+pp],a3=al[384+pp];
      y0.x+=a0*r0; y0.y+=a0*r1; y1.x+=a1*r0; y1.y+=a1*r1;
      y2.x+=a2*r0; y2.y+=a2*r1; y3.x+=a3*r0; y3.y+=a3*r1;
    }
    yb0=y0; yb1=y1; yb2=y2; yb3=y3;
    if (half==0){
      float2* Yw=(float2*)(scratch+w2*512);
      Yw[lane]=y0; Yw[64+lane]=y1; Yw[128+lane]=y2; Yw[192+lane]=y3;
    }
  }
  __syncthreads();
  if (half==1){
    float2* Yw=(float2*)(scratch+w2*512);
    float2 t;
    t=Yw[lane];     t.x+=yb0.x; t.y+=yb0.y; Yw[lane]=t;
    t=Yw[64+lane];  t.x+=yb1.x; t.y+=yb1.y; Yw[64+lane]=t;
    t=Yw[128+lane]; t.x+=yb2.x; t.y+=yb2.y; Yw[128+lane]=t;
    t=Yw[192+lane]; t.x+=yb3.x; t.y+=yb3.y; Yw[192+lane]=t;
  }
  __syncthreads();
  // phase14: agg L1 (2 chains, gelu folded)
  {
    const int r=tid>>7, j=tid&127, h=j>>5, d=j&31;
    const float4* y4=(const float4*)(scratch + r*512 + h*128);
    const float* Wp = WvC + 16384 + (h*128)*32 + d;
    float aa=bv2[128+j], ab=0.f;
#pragma unroll 2
    for (int i=0;i<32;i+=2){
      float4 yv=y4[i]; int cc=4*i;
      aa += yv.x*Wp[cc*32]+yv.y*Wp[(cc+1)*32]+yv.z*Wp[(cc+2)*32]+yv.w*Wp[(cc+3)*32];
      float4 yv2=y4[i+1]; int c2=4*i+4;
      ab += yv2.x*Wp[c2*32]+yv2.y*Wp[(c2+1)*32]+yv2.z*Wp[(c2+2)*32]+yv2.w*Wp[(c2+3)*32];
    }
    rowb[tid]=gelu_f(aa+ab);
  }
  __syncthreads();
  // phase15: gemv128 out_nw L1 (2 chains)
  {
    const int r=tid>>7, j=tid&127;
    const float4* xb=(const float4*)(rowb+r*128);
    const float* W=out_nw+16384;
    float aa=out_nb[128+j], ab=0.f;
#pragma unroll 2
    for (int i=0;i<32;i+=2){
      float4 bv_=xb[i]; int cc=4*i;
      aa += bv_.x*W[cc*128+j]+bv_.y*W[(cc+1)*128+j]+bv_.z*W[(cc+2)*128+j]+bv_.w*W[(cc+3)*128+j];
      float4 bv2_=xb[i+1]; int c2=4*i+4;
      ab += bv2_.x*W[c2*128+j]+bv2_.y*W[(c2+1)*128+j]+bv2_.z*W[(c2+2)*128+j]+bv2_.w*W[(c2+3)*128+j];
    }
    rowa[tid]=aa+ab;
  }
  __syncthreads();
  // phase16: final LN + logits
  if (half==0){
    float sn=sigm(skip_n[1]), os=1.f-sn;
    const float* A=rowa+w2*128; const float* Bx=xA+w2*128;
    float t0=sn*A[lane]+os*Bx[lane]+Bx[lane];
    float t1=sn*A[lane+64]+os*Bx[lane+64]+Bx[lane+64];
    float m=wsum(t0+t1)*(1.f/128.f);
    float d0=t0-m,d1=t1-m;
    float var=wsum(d0*d0+d1*d1)*(1.f/128.f);
    float inv=rsqrtf(var+1e-5f);
    float xv0=elu_f(d0*inv*ln_ng[128+lane]+ln_nbeta[128+lane]);
    float xv1=elu_f(d1*inv*ln_ng[128+lane+64]+ln_nbeta[128+lane+64]);
    float a0=xv0*cls_w[lane*2]  +xv1*cls_w[(lane+64)*2];
    float a1=xv0*cls_w[lane*2+1]+xv1*cls_w[(lane+64)*2+1];
    a0=wsum(a0); a1=wsum(a1);
    if (lane==0){ out[b*2]=a0+cls_b[0]; out[b*2+1]=a1+cls_b[1]; }
  }
  // ---- epilogue: fill this block's att slice (b in [24+cid*4, +4), clamped) ----
  {
    float4* att4 = reinterpret_cast<float4*>(out + 4096);
    const long b0 = 24 + (long)cid*4;
#pragma unroll
    for (int r=0;r<4;r++){
      long bb = b0 + r;
      if (bb >= 2048) break;
      long base = bb*11449L;
      for (int i=tid;i<11449;i+=512){
        float v=(i>=1&&i<107)?(1.f/217088.f):(1.f/107.f);
        nt_store4(&att4[base+i], v);
      }
    }
  }
}

__global__ __launch_bounds__(256) void prep(
  const float* __restrict__ news_emb,
  const float* __restrict__ ctx_w, const float* __restrict__ ctx_b,
  const float* __restrict__ enc_w, const float* __restrict__ enc_b,
  const float* __restrict__ enc_g, const float* __restrict__ enc_beta,
  const float* __restrict__ proj_w, const float* __restrict__ proj_b,
  const float* __restrict__ base_embs,
  const float* __restrict__ fus_w, const float* __restrict__ fus_b,
  const float* __restrict__ lin_pw, const float* __restrict__ lin_pb,
  const float* __restrict__ kqv_nw, const float* __restrict__ kqv_nb,
  const float* __restrict__ kqv_pw, const float* __restrict__ kqv_pb,
  const float* __restrict__ a_rel, const float* __restrict__ m_rel,
  const float* __restrict__ p_rel,
  float* __restrict__ Wcomb, float* __restrict__ bcomb,
  float* __restrict__ WvC, float* __restrict__ bv2,
  float* __restrict__ Wnv, float* __restrict__ bnv,
  float* __restrict__ AU, float* __restrict__ AUT, float* __restrict__ sa1,
  float* __restrict__ xn_enc, float* __restrict__ Vv,
  float* __restrict__ B1v, float* __restrict__ sb1)
{
  __shared__ __align__(16) float pool[6400];
  const int blk=blockIdx.x, tid=threadIdx.x, lane=tid&63, wid=tid>>6;
  if (blk < 135){
    float* sh  = pool;
    float* row1= pool+2048;
    float* row2= pool+2176;
    float* row3= pool+2304;
    float* red = pool+2432;
    if (blk < 16){
      int l=blk>>3, jq=blk&7, h=jq>>1, cc0=(jq&1)*64;
      float* wk = sh;
      float ps = p_rel[(l*2+1)*4+h]*0.17677669529663687f;
      for (int idx=tid; idx<2048; idx+=256){
        int e=idx>>6, cl=idx&63;
        float acc=0.f;
#pragma unroll
        for (int d=0;d<32;d++)
          acc += kqv_pw[(long)l*49152 + (cc0+cl)*384 + h*32 + d]
               * a_rel[((l*2+1)*4+h)*1024 + d*32 + e];
        wk[e*64+cl]=acc*ps;
      }
      __syncthreads();
      for (int idx=tid; idx<8192; idx+=256){
        int c=idx>>6, jl=idx&63;
        float acc=0.f;
#pragma unroll
        for (int e=0;e<32;e++) acc += kqv_nw[(long)l*49152 + c*384 + 128 + h*32 + e]*wk[e*64+jl];
        Wcomb[(long)l*65536 + c*512 + h*128 + cc0 + jl]=acc;
      }
      if (tid<64){
        float acc=0.f;
#pragma unroll
        for (int e=0;e<32;e++) acc += kqv_nb[l*384 + 128 + h*32 + e]*wk[e*64+tid];
        bcomb[l*512 + h*128 + cc0 + tid]=acc;
      }
    } else if (blk < 24){
      int t=blk-16, l=t>>2, h=t&3;
      float* rl = sh;
      for (int i=tid;i<1024;i+=256) rl[i]=m_rel[((l*2+1)*4+h)*1024+i];
      __syncthreads();
      for (int idx=tid; idx<4096; idx+=256){
        int cc=idx>>5, d=idx&31;
        float acc=0.f;
#pragma unroll
        for (int dp=0;dp<32;dp++) acc += kqv_pw[(long)l*49152 + cc*384 + 256 + h*32 + dp]*rl[dp*32+d];
        WvC[l*16384 + (h*128+cc)*32 + d]=acc;
      }
    } else if (blk==24){
      {
        int l=tid>>7, j=tid&127, h=(j>>5)&3, d=j&31;
        float acc=0.f;
#pragma unroll
        for (int dp=0;dp<32;dp++) acc += kqv_pb[l*384+256+h*32+dp]*m_rel[((l*2+1)*4+h)*1024+dp*32+d];
        bv2[l*128+j]=acc;
      }
      if (tid < 128){
        int j=tid, h=j>>5, d=j&31;
        float acc=0.f;
#pragma unroll
        for (int dp=0;dp<32;dp++) acc += kqv_nb[256+h*32+dp]*m_rel[h*1024+dp*32+d];
        bnv[j]=acc;
      }
    } else if (blk < 29){
      int h=blk-25;
      float* rl=sh;
      for (int i=tid;i<1024;i+=256) rl[i]=m_rel[h*1024+i];
      __syncthreads();
      for (int idx=tid; idx<4096; idx+=256){
        int c=idx>>5, d=idx&31;
        float acc=0.f;
#pragma unroll
        for (int dp=0;dp<32;dp++) acc += kqv_nw[c*384+256+h*32+dp]*rl[dp*32+d];
        Wnv[c*128 + h*32 + d]=acc;
      }
    } else {
      int p = blk-29;
      float* xs1=pool;
      int j=tid&127, kg=tid>>7;
      for (int i=tid;i<1024;i+=256) xs1[i]=base_embs[(long)p*1024+i];
      __syncthreads();
      float acc=0.f;
#pragma unroll 4
      for (int k=0;k<512;k++) acc += xs1[kg*512+k]*proj_w[(long)(kg*512+k)*128+j];
      red[tid]=acc; __syncthreads();
      if (tid<128) row1[tid]=red[tid]+red[tid+128]+proj_b[tid];
      __syncthreads();
      acc=0.f;
#pragma unroll 4
      for (int i=0;i<64;i++) acc += row1[kg*64+i]*fus_w[(long)(kg*64+i)*128+j];
      red[tid]=acc; __syncthreads();
      if (tid<128) row2[tid]=red[tid]+red[tid+128]+fus_b[tid];
      __syncthreads();
      acc=0.f;
#pragma unroll 4
      for (int i=0;i<64;i++) acc += row2[kg*64+i]*lin_pw[(long)(kg*64+i)*128+j];
      red[tid]=acc; __syncthreads();
      if (tid<128) row3[tid]=red[tid]+red[tid+128];
      __syncthreads();
      if (wid==0){
        float t0=row3[lane], t1=row3[lane+64];
        float m=wsum(t0+t1)*(1.f/128.f);
        t0-=m; t1-=m;
        float ssq=wsum(t0*t0+t1*t1);
        row3[lane]=t0; row3[lane+64]=t1;
        if (lane==0) sa1[p]=ssq;
      }
      __syncthreads();
      if (tid<64){
        float4 v = make_float4(row3[2*tid],row3[2*tid+1],row2[2*tid],row2[2*tid+1]);
        ((float4*)AU)[p*64+tid]=v;
        ((float4*)AUT)[tid*128+p]=v;
      }
    }
  } else {
    float* xs   = pool;
    float* redL = pool+4096;
    float* rowsC= pool+5120;
    float* Vraw = pool+5632;
    float* bVbL = pool+6144;
    float* bB1L = pool+6272;
    const int r0=(blk-135)*4;
    const int j=tid&127, kg=tid>>7;
    for (int r=0;r<4;r++){
      float4 v=*(const float4*)(news_emb+(long)(r0+r)*1024+tid*4);
      *(float4*)(&xs[r*1024+tid*4])=v;
    }
    {
      float acc=0.f;
#pragma unroll 4
      for (int i=0;i<64;i++) acc += ctx_b[kg*64+i]*fus_w[(128+kg*64+i)*128+j];
      redL[tid]=acc; __syncthreads();
      if (tid<128) bVbL[tid]=redL[tid]+redL[128+tid];
      __syncthreads();
      acc=0.f;
#pragma unroll 4
      for (int i=0;i<64;i++) acc += bVbL[kg*64+i]*lin_pw[(kg*64+i)*128+j];
      redL[tid]=acc; __syncthreads();
      if (tid<128) bB1L[tid]=redL[tid]+redL[128+tid]+lin_pb[tid];
      __syncthreads();
    }
    float ae0=0,ae1=0,ae2=0,ae3=0, ac0=0,ac1=0,ac2=0,ac3=0;
    {
      const float* We=enc_w+(long)(kg*512)*128+j;
      const float* Wc=ctx_w+(long)(kg*512)*128+j;
#pragma unroll 2
      for (int k=0;k<512;k++){
        float we=We[(long)k*128], wc=Wc[(long)k*128];
        float v0=xs[kg*512+k], v1=xs[1024+kg*512+k], v2=xs[2048+kg*512+k], v3=xs[3072+kg*512+k];
        ae0+=v0*we; ae1+=v1*we; ae2+=v2*we; ae3+=v3*we;
        ac0+=v0*wc; ac1+=v1*wc; ac2+=v2*wc; ac3+=v3*wc;
      }
    }
    redL[tid]=ae0; redL[256+tid]=ae1; redL[512+tid]=ae2; redL[768+tid]=ae3;
    __syncthreads();
    {
      float t0=redL[wid*256+lane]+redL[wid*256+128+lane]+enc_b[lane];
      float t1=redL[wid*256+lane+64]+redL[wid*256+128+lane+64]+enc_b[lane+64];
      float m=wsum(t0+t1)*(1.f/128.f);
      float d0=t0-m,d1=t1-m;
      float var=wsum(d0*d0+d1*d1)*(1.f/128.f);
      float inv=rsqrtf(var+1e-5f);
      xn_enc[(long)(r0+wid)*128+lane]   =elu_f(d0*inv*enc_g[lane]   +enc_beta[lane]);
      xn_enc[(long)(r0+wid)*128+lane+64]=elu_f(d1*inv*enc_g[lane+64]+enc_beta[lane+64]);
    }
    __syncthreads();
    redL[tid]=ac0; redL[256+tid]=ac1; redL[512+tid]=ac2; redL[768+tid]=ac3;
    __syncthreads();
    for (int i=tid;i<512;i+=256){
      int r=i>>7,jj=i&127;
      rowsC[r*128+jj]=redL[r*256+jj]+redL[r*256+128+jj];
    }
    __syncthreads();
    {
      const float* Wf=fus_w+(128+kg*64)*128+j;
      float a0=0,a1=0,a2=0,a3=0;
#pragma unroll 4
      for (int i=0;i<64;i++){
        float wv=Wf[i*128];
        a0+=rowsC[kg*64+i]*wv; a1+=rowsC[128+kg*64+i]*wv;
        a2+=rowsC[256+kg*64+i]*wv; a3+=rowsC[384+kg*64+i]*wv;
      }
      redL[tid]=a0; redL[256+tid]=a1; redL[512+tid]=a2; redL[768+tid]=a3;
    }
    __syncthreads();
    for (int i=tid;i<512;i+=256){
      int r=i>>7,jj=i&127;
      float v=redL[r*256+jj]+redL[r*256+128+jj];
      Vraw[r*128+jj]=v;
      Vv[(long)(r0+r)*128+jj]=v+bVbL[jj];
    }
    __syncthreads();
    {
      const float* Wl=lin_pw+(kg*64)*128+j;
      float a0=0,a1=0,a2=0,a3=0;
#pragma unroll 4
      for (int i=0;i<64;i++){
        float wv=Wl[i*128];
        a0+=Vraw[kg*64+i]*wv; a1+=Vraw[128+kg*64+i]*wv;
        a2+=Vraw[256+kg*64+i]*wv; a3+=Vraw[384+kg*64+i]*wv;
      }
      redL[tid]=a0; redL[256+tid]=a1; redL[512+tid]=a2; redL[768+tid]=a3;
    }
    __syncthreads();
    {
      float t0=redL[wid*256+lane]+redL[wid*256+128+lane]+bB1L[lane];
      float t1=redL[wid*256+lane+64]+redL[wid*256+128+lane+64]+bB1L[lane+64];
      float m=wsum(t0+t1)*(1.f/128.f);
      t0-=m; t1-=m;
      float ssq=wsum(t0*t0+t1*t1);
      B1v[(long)(r0+wid)*128+lane]=t0;
      B1v[(long)(r0+wid)*128+lane+64]=t1;
      if (lane==0) sb1[r0+wid]=ssq;
    }
  }
}

__global__ __launch_bounds__(256) void fill_att2(float4* __restrict__ att4){
  const float v1 = 1.f/107.f, v2 = 1.f/217088.f;
  long base = (long)blockIdx.x*11449;
  for (int i=threadIdx.x; i<11449; i+=256){
    float v = (i>=1 && i<107) ? v2 : v1;
    nt_store4(&att4[base+i], v);
  }
}

extern "C" void kernel_launch(void* const* d_in, const int* in_sizes, int n_in,
                              void* d_out, int out_size, void* d_ws, size_t ws_size,
                              hipStream_t stream) {
  const float* news_emb = (const float*)d_in[0];
  const float* base_embs= (const float*)d_in[1];
  const float* ctx_w  = (const float*)d_in[2];
  const float* ctx_b  = (const float*)d_in[3];
  const float* proj_w = (const float*)d_in[4];
  const float* proj_b = (const float*)d_in[5];
  const float* fus_w  = (const float*)d_in[6];
  const float* fus_b  = (const float*)d_in[7];
  const float* enc_w  = (const float*)d_in[8];
  const float* enc_b  = (const float*)d_in[9];
  const float* enc_g  = (const float*)d_in[10];
  const float* enc_beta=(const float*)d_in[11];
  const float* lin_nw = (const float*)d_in[12];
  const float* lin_nb = (const float*)d_in[13];
  const float* lin_ng = (const float*)d_in[14];
  const float* lin_nbeta=(const float*)d_in[15];
  const float* kqv_nw = (const float*)d_in[16];
  const float* kqv_nb = (const float*)d_in[17];
  const float* out_nw = (const float*)d_in[18];
  const float* out_nb = (const float*)d_in[19];
  const float* skip_n = (const float*)d_in[20];
  const float* ln_ng  = (const float*)d_in[21];
  const float* ln_nbeta=(const float*)d_in[22];
  const float* lin_pw = (const float*)d_in[23];
  const float* lin_pb = (const float*)d_in[24];
  const float* lin_pg = (const float*)d_in[25];
  const float* lin_pbeta=(const float*)d_in[26];
  const float* kqv_pw = (const float*)d_in[27];
  const float* kqv_pb = (const float*)d_in[28];
  const float* out_pw = (const float*)d_in[29];
  const float* out_pb = (const float*)d_in[30];
  const float* skip_p = (const float*)d_in[31];
  const float* ln_pg  = (const float*)d_in[32];
  const float* ln_pbeta=(const float*)d_in[33];
  const float* a_rel  = (const float*)d_in[34];
  const float* m_rel  = (const float*)d_in[35];
  const float* p_rel  = (const float*)d_in[36];
  const float* cls_w  = (const float*)d_in[37];
  const float* cls_b  = (const float*)d_in[38];
  (void)in_sizes; (void)n_in; (void)out_size; (void)d_ws; (void)ws_size;

  float* out = (float*)d_out;
  float* S = out + 4096;            // scratch inside b<24 att zone; head-filled last
  float* xn_enc = S + 0;
  float* Vv     = S + 262144;
  float* B1v    = S + 524288;
  float* sb1    = S + 786432;
  float* sa1    = S + 788480;
  float* AU     = S + 788608;
  float* AUT    = S + 815744;
  float* WvC    = S + 848512;
  float* bv2    = S + 881280;
  float* Wnv    = S + 881536;
  float* bnv    = S + 897920;
  float* Wcomb  = S + 898048;
  float* bcomb  = S + 1029120;

  dim3 blk(256), blkL(512);
  prep<<<647,blk,0,stream>>>(news_emb,ctx_w,ctx_b,enc_w,enc_b,enc_g,enc_beta,
      proj_w,proj_b,base_embs,fus_w,fus_b,lin_pw,lin_pb,
      kqv_nw,kqv_nb,kqv_pw,kqv_pb,a_rel,m_rel,p_rel,
      Wcomb,bcomb,WvC,bv2,Wnv,bnv,AU,AUT,sa1,xn_enc,Vv,B1v,sb1);
  mega<<<512,blkL,0,stream>>>(xn_enc,Vv,B1v,sb1,AU,AUT,sa1,Wcomb,bcomb,WvC,bv2,Wnv,bnv,
      lin_nw,lin_nb,lin_ng,lin_nbeta,lin_pg,lin_pbeta,ln_pg,ln_pbeta,
      out_nw,out_nb,out_pw,out_pb,skip_n,skip_p,ln_ng,ln_nbeta,cls_w,cls_b,out);
  fill_att2<<<24,blk,0,stream>>>(reinterpret_cast<float4*>(S));
}